// Round 1
// baseline (136.719 us; speedup 1.0000x reference)
//
#include <hip/hip_runtime.h>

#define N_NODES 40000
#define N_EDGES 160000
#define N_FEATS 74
#define NH 3
#define DD 1024
#define HD 3072
#define N_GRAPHS 800

__device__ __forceinline__ float waveReduceSum(float v) {
    #pragma unroll
    for (int off = 32; off > 0; off >>= 1)
        v += __shfl_down(v, off, 64);
    return v;
}

// zero accumulators
__global__ void kZero(float* __restrict__ ssum, float* __restrict__ ygr, int* __restrict__ cnt) {
    int i = blockIdx.x * blockDim.x + threadIdx.x;
    if (i < N_NODES * NH) ssum[i] = 0.f;
    if (i < N_GRAPHS) { ygr[i] = 0.f; cnt[i] = 0; }
}

// v = W1 @ W2  (3072), c0 = b1.W2 + b2
__global__ void kV(const float* __restrict__ W1, const float* __restrict__ W2,
                   const float* __restrict__ b1, const float* __restrict__ b2,
                   float* __restrict__ v, float* __restrict__ c0) {
    int w = blockIdx.x * 4 + (threadIdx.x >> 6);
    int lane = threadIdx.x & 63;
    if (w < HD) {
        const float* row = W1 + (size_t)w * DD;
        float acc = 0.f;
        for (int t = lane; t < DD; t += 64) acc += row[t] * W2[t];
        acc = waveReduceSum(acc);
        if (lane == 0) v[w] = acc;
    } else if (w == HD) {
        float acc = 0.f;
        for (int t = lane; t < DD; t += 64) acc += b1[t] * W2[t];
        acc = waveReduceSum(acc);
        if (lane == 0) *c0 = acc + b2[0];
    }
}

// Wl/Wr/Wv [74,3] packed as wl9[f*9 + {0..2,3..5,6..8}], bgv = bias_gat . v
__global__ void kProj(const float* __restrict__ W, const float* __restrict__ al,
                      const float* __restrict__ ar, const float* __restrict__ v,
                      const float* __restrict__ bias, float* __restrict__ wl9,
                      float* __restrict__ bgv) {
    int w = blockIdx.x * 4 + (threadIdx.x >> 6);
    int lane = threadIdx.x & 63;
    if (w < N_FEATS * NH) {
        int f = w / 3, h = w - f * 3;
        const float* rw = W + (size_t)f * HD + h * DD;
        const float* pl = al + h * DD;
        const float* pr = ar + h * DD;
        const float* pv = v + h * DD;
        float aL = 0.f, aR = 0.f, aV = 0.f;
        for (int t = lane; t < DD; t += 64) {
            float x = rw[t];
            aL += x * pl[t]; aR += x * pr[t]; aV += x * pv[t];
        }
        aL = waveReduceSum(aL); aR = waveReduceSum(aR); aV = waveReduceSum(aV);
        if (lane == 0) {
            wl9[f * 9 + h]     = aL;
            wl9[f * 9 + 3 + h] = aR;
            wl9[f * 9 + 6 + h] = aV;
        }
    } else if (w == N_FEATS * NH) {
        float acc = 0.f;
        for (int t = lane; t < HD; t += 64) acc += bias[t] * v[t];
        acc = waveReduceSum(acc);
        if (lane == 0) *bgv = acc;
    }
}

// per-node: el/er/hv = feats @ [Wl|Wr|Wv]; also count nodes per graph
__global__ __launch_bounds__(256) void kNode(const float* __restrict__ feats,
                      const float* __restrict__ wl9, const int* __restrict__ gids,
                      float* __restrict__ el, float* __restrict__ er,
                      float* __restrict__ hv, int* __restrict__ cnt) {
    __shared__ float tile[256 * 75];   // +1 pad: stride 75 -> conflict-free
    __shared__ float lw[N_FEATS * 9];
    int t = threadIdx.x;
    int base = blockIdx.x * 256;
    int nvalid = min(256, N_NODES - base);
    for (int i = t; i < N_FEATS * 9; i += 256) lw[i] = wl9[i];
    int total = nvalid * N_FEATS;
    const float* srcp = feats + (size_t)base * N_FEATS;
    for (int i = t; i < total; i += 256) {
        int node = i / N_FEATS;
        int f = i - node * N_FEATS;
        tile[node * 75 + f] = srcp[i];
    }
    __syncthreads();
    if (t < nvalid) {
        float a0=0,a1=0,a2=0,a3=0,a4=0,a5=0,a6=0,a7=0,a8=0;
        const float* row = tile + t * 75;
        #pragma unroll 2
        for (int f = 0; f < N_FEATS; ++f) {
            float x = row[f];
            const float* wp = lw + f * 9;
            a0 += x * wp[0]; a1 += x * wp[1]; a2 += x * wp[2];
            a3 += x * wp[3]; a4 += x * wp[4]; a5 += x * wp[5];
            a6 += x * wp[6]; a7 += x * wp[7]; a8 += x * wp[8];
        }
        int i = base + t;
        el[i*3+0]=a0; el[i*3+1]=a1; el[i*3+2]=a2;
        er[i*3+0]=a3; er[i*3+1]=a4; er[i*3+2]=a5;
        hv[i*3+0]=a6; hv[i*3+1]=a7; hv[i*3+2]=a8;
        atomicAdd(&cnt[gids[i]], 1);
    }
}

// per-edge pass 1: ex = exp(leaky_relu(el[src]+er[dst])), accumulate denominators
__global__ void kEdge1(const int* __restrict__ src, const int* __restrict__ dst,
                       const float* __restrict__ el, const float* __restrict__ er,
                       float* __restrict__ exb, float* __restrict__ ssum) {
    int e = blockIdx.x * blockDim.x + threadIdx.x;
    if (e >= N_EDGES) return;
    int s = src[e], d = dst[e];
    #pragma unroll
    for (int h = 0; h < NH; ++h) {
        float x = el[s * 3 + h] + er[d * 3 + h];
        x = x > 0.f ? x : 0.2f * x;
        float ex = expf(x);
        exb[e * 3 + h] = ex;
        atomicAdd(&ssum[d * 3 + h], ex);
    }
}

// per-edge pass 2: sum_h alpha*hv[src] -> per-graph accumulator
__global__ void kEdge2(const int* __restrict__ src, const int* __restrict__ dst,
                       const int* __restrict__ gids,
                       const float* __restrict__ exb, const float* __restrict__ ssum,
                       const float* __restrict__ hv, float* __restrict__ ygr) {
    int e = blockIdx.x * blockDim.x + threadIdx.x;
    if (e >= N_EDGES) return;
    int s = src[e], d = dst[e];
    float c = 0.f;
    #pragma unroll
    for (int h = 0; h < NH; ++h)
        c += exb[e * 3 + h] / ssum[d * 3 + h] * hv[s * 3 + h];
    atomicAdd(&ygr[gids[d]], c);
}

// y[g] = ygr[g]/cnt + bias_gat.v + (b1.W2 + b2)
__global__ void kFinal(const float* __restrict__ ygr, const int* __restrict__ cnt,
                       const float* __restrict__ bgv, const float* __restrict__ c0,
                       float* __restrict__ y) {
    int g = blockIdx.x * blockDim.x + threadIdx.x;
    if (g < N_GRAPHS) {
        float cc = (float)max(cnt[g], 1);
        y[g] = ygr[g] / cc + bgv[0] + c0[0];
    }
}

extern "C" void kernel_launch(void* const* d_in, const int* in_sizes, int n_in,
                              void* d_out, int out_size, void* d_ws, size_t ws_size,
                              hipStream_t stream) {
    const float* feats = (const float*)d_in[0];
    const float* W     = (const float*)d_in[1];
    const float* al    = (const float*)d_in[2];
    const float* ar    = (const float*)d_in[3];
    const float* bias  = (const float*)d_in[4];
    const float* W1    = (const float*)d_in[5];
    const float* b1    = (const float*)d_in[6];
    const float* W2    = (const float*)d_in[7];
    const float* b2    = (const float*)d_in[8];
    const int*   src   = (const int*)d_in[9];
    const int*   dst   = (const int*)d_in[10];
    const int*   gids  = (const int*)d_in[11];

    float* ws   = (float*)d_ws;
    float* v    = ws;                  // 3072
    float* wl9  = v + 3072;            // 672 (666 used)
    float* el   = wl9 + 672;           // 120000
    float* er   = el + 120000;         // 120000
    float* hv   = er + 120000;         // 120000
    float* exb  = hv + 120000;         // 480000
    float* ssum = exb + 480000;        // 120000
    float* ygr  = ssum + 120000;       // 800
    int*   cnt  = (int*)(ygr + 800);   // 800
    float* c0   = (float*)(cnt + 800); // 1
    float* bgv  = c0 + 1;              // 1

    float* y = (float*)d_out;

    hipLaunchKernelGGL(kZero, dim3((N_NODES * NH + 255) / 256), dim3(256), 0, stream,
                       ssum, ygr, cnt);
    hipLaunchKernelGGL(kV, dim3((HD + 1 + 3) / 4), dim3(256), 0, stream,
                       W1, W2, b1, b2, v, c0);
    hipLaunchKernelGGL(kProj, dim3((N_FEATS * NH + 1 + 3) / 4), dim3(256), 0, stream,
                       W, al, ar, v, bias, wl9, bgv);
    hipLaunchKernelGGL(kNode, dim3((N_NODES + 255) / 256), dim3(256), 0, stream,
                       feats, wl9, gids, el, er, hv, cnt);
    hipLaunchKernelGGL(kEdge1, dim3((N_EDGES + 255) / 256), dim3(256), 0, stream,
                       src, dst, el, er, exb, ssum);
    hipLaunchKernelGGL(kEdge2, dim3((N_EDGES + 255) / 256), dim3(256), 0, stream,
                       src, dst, gids, exb, ssum, hv, ygr);
    hipLaunchKernelGGL(kFinal, dim3((N_GRAPHS + 255) / 256), dim3(256), 0, stream,
                       ygr, cnt, bgv, c0, y);
}

// Round 2
// 120.025 us; speedup vs baseline: 1.1391x; 1.1391x over previous
//
#include <hip/hip_runtime.h>

#define N_NODES 40000
#define N_EDGES 160000
#define N_FEATS 74
#define NH 3
#define DD 1024
#define HD 3072
#define N_GRAPHS 800

__device__ __forceinline__ float waveReduceSum(float v) {
    #pragma unroll
    for (int off = 32; off > 0; off >>= 1)
        v += __shfl_down(v, off, 64);
    return v;
}

__device__ __forceinline__ float lrelu02(float x) {
    return x > 0.f ? x : 0.2f * x;
}

// zero accumulators: ssum4 (160000 f), outn (40000 f), ygr (800 f), cnt (800 i)
__global__ void kZero(float* __restrict__ ssum4, float* __restrict__ outn,
                      float* __restrict__ ygr, int* __restrict__ cnt) {
    int i = blockIdx.x * blockDim.x + threadIdx.x;
    if (i < N_NODES * 4) ssum4[i] = 0.f;
    if (i < N_NODES) outn[i] = 0.f;
    if (i < N_GRAPHS) { ygr[i] = 0.f; cnt[i] = 0; }
}

// v = W1 @ W2  (3072), c0 = b1.W2 + b2
__global__ void kV(const float* __restrict__ W1, const float* __restrict__ W2,
                   const float* __restrict__ b1, const float* __restrict__ b2,
                   float* __restrict__ v, float* __restrict__ c0) {
    int w = blockIdx.x * 4 + (threadIdx.x >> 6);
    int lane = threadIdx.x & 63;
    if (w < HD) {
        const float* row = W1 + (size_t)w * DD;
        float acc = 0.f;
        for (int t = lane; t < DD; t += 64) acc += row[t] * W2[t];
        acc = waveReduceSum(acc);
        if (lane == 0) v[w] = acc;
    } else if (w == HD) {
        float acc = 0.f;
        for (int t = lane; t < DD; t += 64) acc += b1[t] * W2[t];
        acc = waveReduceSum(acc);
        if (lane == 0) *c0 = acc + b2[0];
    }
}

// Wl/Wr/Wv [74,3] packed as wl9[f*9 + {0..2,3..5,6..8}], bgv = bias_gat . v
__global__ void kProj(const float* __restrict__ W, const float* __restrict__ al,
                      const float* __restrict__ ar, const float* __restrict__ v,
                      const float* __restrict__ bias, float* __restrict__ wl9,
                      float* __restrict__ bgv) {
    int w = blockIdx.x * 4 + (threadIdx.x >> 6);
    int lane = threadIdx.x & 63;
    if (w < N_FEATS * NH) {
        int f = w / 3, h = w - f * 3;
        const float* rw = W + (size_t)f * HD + h * DD;
        const float* pl = al + h * DD;
        const float* pr = ar + h * DD;
        const float* pv = v + h * DD;
        float aL = 0.f, aR = 0.f, aV = 0.f;
        for (int t = lane; t < DD; t += 64) {
            float x = rw[t];
            aL += x * pl[t]; aR += x * pr[t]; aV += x * pv[t];
        }
        aL = waveReduceSum(aL); aR = waveReduceSum(aR); aV = waveReduceSum(aV);
        if (lane == 0) {
            wl9[f * 9 + h]     = aL;
            wl9[f * 9 + 3 + h] = aR;
            wl9[f * 9 + 6 + h] = aV;
        }
    } else if (w == N_FEATS * NH) {
        float acc = 0.f;
        for (int t = lane; t < HD; t += 64) acc += bias[t] * v[t];
        acc = waveReduceSum(acc);
        if (lane == 0) *bgv = acc;
    }
}

// per-node: el/er/hv = feats @ [Wl|Wr|Wv] -> float4-padded; count nodes per graph
__global__ __launch_bounds__(256) void kNode(const float* __restrict__ feats,
                      const float* __restrict__ wl9, const int* __restrict__ gids,
                      float4* __restrict__ el4, float4* __restrict__ er4,
                      float4* __restrict__ hv4, int* __restrict__ cnt) {
    __shared__ float tile[256 * 75];   // +1 pad: stride 75 -> conflict-free
    __shared__ float lw[N_FEATS * 9];
    int t = threadIdx.x;
    int base = blockIdx.x * 256;
    int nvalid = min(256, N_NODES - base);
    for (int i = t; i < N_FEATS * 9; i += 256) lw[i] = wl9[i];
    int total = nvalid * N_FEATS;
    const float* srcp = feats + (size_t)base * N_FEATS;
    for (int i = t; i < total; i += 256) {
        int node = i / N_FEATS;
        int f = i - node * N_FEATS;
        tile[node * 75 + f] = srcp[i];
    }
    __syncthreads();
    if (t < nvalid) {
        float a0=0,a1=0,a2=0,a3=0,a4=0,a5=0,a6=0,a7=0,a8=0;
        const float* row = tile + t * 75;
        #pragma unroll 2
        for (int f = 0; f < N_FEATS; ++f) {
            float x = row[f];
            const float* wp = lw + f * 9;
            a0 += x * wp[0]; a1 += x * wp[1]; a2 += x * wp[2];
            a3 += x * wp[3]; a4 += x * wp[4]; a5 += x * wp[5];
            a6 += x * wp[6]; a7 += x * wp[7]; a8 += x * wp[8];
        }
        int i = base + t;
        el4[i] = make_float4(a0, a1, a2, 0.f);
        er4[i] = make_float4(a3, a4, a5, 0.f);
        hv4[i] = make_float4(a6, a7, a8, 0.f);
        atomicAdd(&cnt[gids[i]], 1);
    }
}

// edge pass 1: accumulate softmax denominators per dst node
__global__ void kDenom(const int* __restrict__ src, const int* __restrict__ dst,
                       const float4* __restrict__ el4, const float4* __restrict__ er4,
                       float* __restrict__ ssum) {
    int e = blockIdx.x * blockDim.x + threadIdx.x;
    if (e >= N_EDGES) return;
    int s = src[e], d = dst[e];
    float4 L = el4[s], R = er4[d];
    atomicAdd(&ssum[d * 4 + 0], expf(lrelu02(L.x + R.x)));
    atomicAdd(&ssum[d * 4 + 1], expf(lrelu02(L.y + R.y)));
    atomicAdd(&ssum[d * 4 + 2], expf(lrelu02(L.z + R.z)));
}

// edge pass 2: recompute ex, c = sum_h alpha*hv[src] -> per-dst-node accumulator
__global__ void kEdge2(const int* __restrict__ src, const int* __restrict__ dst,
                       const float4* __restrict__ el4, const float4* __restrict__ er4,
                       const float4* __restrict__ ssum4, const float4* __restrict__ hv4,
                       float* __restrict__ outn) {
    int e = blockIdx.x * blockDim.x + threadIdx.x;
    if (e >= N_EDGES) return;
    int s = src[e], d = dst[e];
    float4 L = el4[s], R = er4[d], S = ssum4[d], V = hv4[s];
    float c = expf(lrelu02(L.x + R.x)) / S.x * V.x
            + expf(lrelu02(L.y + R.y)) / S.y * V.y
            + expf(lrelu02(L.z + R.z)) / S.z * V.z;
    atomicAdd(&outn[d], c);
}

// node pass: pool per-node scalars into per-graph bins (50-deep contention only)
__global__ void kPool(const float* __restrict__ outn, const int* __restrict__ gids,
                      float* __restrict__ ygr) {
    int i = blockIdx.x * blockDim.x + threadIdx.x;
    if (i < N_NODES) atomicAdd(&ygr[gids[i]], outn[i]);
}

// y[g] = ygr[g]/cnt + bias_gat.v + (b1.W2 + b2)
__global__ void kFinal(const float* __restrict__ ygr, const int* __restrict__ cnt,
                       const float* __restrict__ bgv, const float* __restrict__ c0,
                       float* __restrict__ y) {
    int g = blockIdx.x * blockDim.x + threadIdx.x;
    if (g < N_GRAPHS) {
        float cc = (float)max(cnt[g], 1);
        y[g] = ygr[g] / cc + bgv[0] + c0[0];
    }
}

extern "C" void kernel_launch(void* const* d_in, const int* in_sizes, int n_in,
                              void* d_out, int out_size, void* d_ws, size_t ws_size,
                              hipStream_t stream) {
    const float* feats = (const float*)d_in[0];
    const float* W     = (const float*)d_in[1];
    const float* al    = (const float*)d_in[2];
    const float* ar    = (const float*)d_in[3];
    const float* bias  = (const float*)d_in[4];
    const float* W1    = (const float*)d_in[5];
    const float* b1    = (const float*)d_in[6];
    const float* W2    = (const float*)d_in[7];
    const float* b2    = (const float*)d_in[8];
    const int*   src   = (const int*)d_in[9];
    const int*   dst   = (const int*)d_in[10];
    const int*   gids  = (const int*)d_in[11];

    float* ws   = (float*)d_ws;
    float* v    = ws;                     // 3072
    float* wl9  = v + 3072;               // 672 (666 used)
    float* el   = wl9 + 672 + 2;          // pad to 16B alignment: 3072+672+2=3746... ensure alignment below
    // re-derive aligned offsets (keep every float4 array 16B aligned):
    float* base = ws;
    float* el4  = base + 4096;            // 160000 (N*4)
    float* er4  = el4 + N_NODES * 4;      // 160000
    float* hv4  = er4 + N_NODES * 4;      // 160000
    float* ss4  = hv4 + N_NODES * 4;      // 160000
    float* outn = ss4 + N_NODES * 4;      // 40000
    float* ygr  = outn + N_NODES;         // 800
    int*   cnt  = (int*)(ygr + 800);      // 800
    float* c0   = (float*)(cnt + 800);    // 1
    float* bgv  = c0 + 1;                 // 1
    v   = base;                           // 3072
    wl9 = base + 3072;                    // 672
    (void)el;

    float* y = (float*)d_out;

    hipLaunchKernelGGL(kZero, dim3((N_NODES * 4 + 255) / 256), dim3(256), 0, stream,
                       ss4, outn, ygr, cnt);
    hipLaunchKernelGGL(kV, dim3((HD + 1 + 3) / 4), dim3(256), 0, stream,
                       W1, W2, b1, b2, v, c0);
    hipLaunchKernelGGL(kProj, dim3((N_FEATS * NH + 1 + 3) / 4), dim3(256), 0, stream,
                       W, al, ar, v, bias, wl9, bgv);
    hipLaunchKernelGGL(kNode, dim3((N_NODES + 255) / 256), dim3(256), 0, stream,
                       feats, wl9, gids, (float4*)el4, (float4*)er4, (float4*)hv4, cnt);
    hipLaunchKernelGGL(kDenom, dim3((N_EDGES + 255) / 256), dim3(256), 0, stream,
                       src, dst, (const float4*)el4, (const float4*)er4, ss4);
    hipLaunchKernelGGL(kEdge2, dim3((N_EDGES + 255) / 256), dim3(256), 0, stream,
                       src, dst, (const float4*)el4, (const float4*)er4,
                       (const float4*)ss4, (const float4*)hv4, outn);
    hipLaunchKernelGGL(kPool, dim3((N_NODES + 255) / 256), dim3(256), 0, stream,
                       outn, gids, ygr);
    hipLaunchKernelGGL(kFinal, dim3((N_GRAPHS + 255) / 256), dim3(256), 0, stream,
                       ygr, cnt, bgv, c0, y);
}